// Round 2
// baseline (10046.332 us; speedup 1.0000x reference)
//
#include <hip/hip_runtime.h>

#define TT 1024
#define BB 256
#define CC 41

__device__ __forceinline__ float sigf(float x) {
    float t = __builtin_amdgcn_exp2f(-1.4426950408889634f * x);
    return __builtin_amdgcn_rcpf(1.0f + t);
}
__device__ __forceinline__ float tanhf_fast(float x) {
    float t = __builtin_amdgcn_exp2f(2.8853900817779268f * x);
    return fmaf(-2.0f, __builtin_amdgcn_rcpf(t + 1.0f), 1.0f);
}
__device__ __forceinline__ float lane_bcast(float v, int k) {
    return __uint_as_float(__builtin_amdgcn_readlane(__float_as_uint(v), k));
}

// ---------------------------------------------------------------------------
// C[M,N] = A[M,K] @ W[N,K]^T + bias[N]
// 128x128 block tile, 256 threads, 8x8 micro-tile (split 4+4 for bank-free LDS
// fragment reads), K staged in chunks of 32.
// ---------------------------------------------------------------------------
template <bool K4>
__global__ __launch_bounds__(256, 2) void gemm_bias_kernel(
    const float* __restrict__ A, const float* __restrict__ W,
    const float* __restrict__ bias, float* __restrict__ C,
    int M, int N, int K)
{
    __shared__ float As[32][132];
    __shared__ float Bs[32][132];
    const int tid = threadIdx.x;
    const int m0 = blockIdx.x * 128;
    const int n0 = blockIdx.y * 128;
    const int ty = tid >> 4;   // 0..15 -> m rows {ty*4..+3} and {64+ty*4..+3}
    const int tx = tid & 15;   // 0..15 -> n cols {tx*4..+3} and {64+tx*4..+3}

    float acc[8][8];
#pragma unroll
    for (int i = 0; i < 8; ++i)
#pragma unroll
        for (int j = 0; j < 8; ++j) acc[i][j] = 0.f;

    for (int k0 = 0; k0 < K; k0 += 32) {
        const int kc = (K - k0 < 32) ? (K - k0) : 32;
        if (K4) {
            // vectorized staging: 128 rows x 32 k = 1024 float4, 4/thread
#pragma unroll
            for (int r = 0; r < 4; ++r) {
                const int lin = tid + r * 256;
                const int m = lin >> 3, c4 = lin & 7;
                const float4 v = *(const float4*)&A[(size_t)(m0 + m) * K + k0 + c4 * 4];
                As[c4 * 4 + 0][m] = v.x; As[c4 * 4 + 1][m] = v.y;
                As[c4 * 4 + 2][m] = v.z; As[c4 * 4 + 3][m] = v.w;
            }
#pragma unroll
            for (int r = 0; r < 4; ++r) {
                const int lin = tid + r * 256;
                const int n = lin >> 3, c4 = lin & 7;
                const float4 v = *(const float4*)&W[(size_t)(n0 + n) * K + k0 + c4 * 4];
                Bs[c4 * 4 + 0][n] = v.x; Bs[c4 * 4 + 1][n] = v.y;
                Bs[c4 * 4 + 2][n] = v.z; Bs[c4 * 4 + 3][n] = v.w;
            }
        } else if (kc == 32) {
#pragma unroll
            for (int r = 0; r < 16; ++r) {
                const int lin = tid + r * 256;
                const int m = lin >> 5, cc = lin & 31;
                As[cc][m] = A[(size_t)(m0 + m) * K + k0 + cc];
            }
#pragma unroll
            for (int r = 0; r < 16; ++r) {
                const int lin = tid + r * 256;
                const int n = lin >> 5, cc = lin & 31;
                Bs[cc][n] = W[(size_t)(n0 + n) * K + k0 + cc];
            }
        } else {
            for (int lin = tid; lin < 128 * kc; lin += 256) {
                const int m = lin / kc, cc = lin - m * kc;
                As[cc][m] = A[(size_t)(m0 + m) * K + k0 + cc];
            }
            for (int lin = tid; lin < 128 * kc; lin += 256) {
                const int n = lin / kc, cc = lin - n * kc;
                Bs[cc][n] = W[(size_t)(n0 + n) * K + k0 + cc];
            }
        }
        __syncthreads();

        for (int kk = 0; kk < kc; ++kk) {
            float a[8], b[8];
            *(float4*)&a[0] = *(const float4*)&As[kk][ty * 4];
            *(float4*)&a[4] = *(const float4*)&As[kk][64 + ty * 4];
            *(float4*)&b[0] = *(const float4*)&Bs[kk][tx * 4];
            *(float4*)&b[4] = *(const float4*)&Bs[kk][64 + tx * 4];
#pragma unroll
            for (int i = 0; i < 8; ++i)
#pragma unroll
                for (int j = 0; j < 8; ++j)
                    acc[i][j] = fmaf(a[i], b[j], acc[i][j]);
        }
        __syncthreads();
    }

    float b0[4], b1[4];
#pragma unroll
    for (int j = 0; j < 4; ++j) {
        b0[j] = bias[n0 + tx * 4 + j];
        b1[j] = bias[n0 + 64 + tx * 4 + j];
    }
#pragma unroll
    for (int i = 0; i < 8; ++i) {
        const int m = m0 + ((i < 4) ? (ty * 4 + i) : (64 + ty * 4 + i - 4));
        float4 v0, v1;
        v0.x = acc[i][0] + b0[0]; v0.y = acc[i][1] + b0[1];
        v0.z = acc[i][2] + b0[2]; v0.w = acc[i][3] + b0[3];
        v1.x = acc[i][4] + b1[0]; v1.y = acc[i][5] + b1[1];
        v1.z = acc[i][6] + b1[2]; v1.w = acc[i][7] + b1[3];
        *(float4*)&C[(size_t)m * N + n0 + tx * 4] = v0;
        *(float4*)&C[(size_t)m * N + n0 + 64 + tx * 4] = v1;
    }
}

// ---------------------------------------------------------------------------
// Recurrence: gx precomputed. One (row, dir) per block, 256 threads = 256
// gates. wh[64] per thread in VGPRs; h broadcast via readlane; single barrier
// per step (double-buffered act, redundant per-wave c/h update).
// ---------------------------------------------------------------------------
__global__ __launch_bounds__(256) void recur_kernel(
    const float* __restrict__ gx,    // [nc,T,512] chunk-local (bias included)
    const float* __restrict__ w_hh,  // [2,256,64]
    float* __restrict__ hout,        // [B,T,128] global
    int c0)
{
    const int bl = blockIdx.x;
    const int dir = blockIdx.y;
    const int tid = threadIdx.x;
    const int lane = tid & 63;

    float wh[64];
    const float* wr = w_hh + ((size_t)dir * 256 + tid) * 64;
#pragma unroll
    for (int k = 0; k < 64; ++k) wh[k] = wr[k];

    __shared__ float act[2][256];
    const float* gxb = gx + ((size_t)bl * TT) * 512 + dir * 256 + tid;
    float* hob = hout + ((size_t)(c0 + bl) * TT) * 128 + dir * 64 + lane;

    float h = 0.f, c = 0.f;
    float g0 = gxb[(size_t)(dir ? (TT - 1) : 0) * 512];
    float g1 = gxb[(size_t)(dir ? (TT - 2) : 1) * 512];

    for (int s = 0; s < TT; ++s) {
        float g2 = 0.f;
        if (s + 2 < TT) {
            const int tn = dir ? (TT - 3 - s) : (s + 2);
            g2 = gxb[(size_t)tn * 512];
        }
        float a0 = g0, a1 = 0.f, a2 = 0.f, a3 = 0.f;
#pragma unroll
        for (int k = 0; k < 64; k += 4) {
            a0 = fmaf(lane_bcast(h, k + 0), wh[k + 0], a0);
            a1 = fmaf(lane_bcast(h, k + 1), wh[k + 1], a1);
            a2 = fmaf(lane_bcast(h, k + 2), wh[k + 2], a2);
            a3 = fmaf(lane_bcast(h, k + 3), wh[k + 3], a3);
        }
        const float a = (a0 + a1) + (a2 + a3);
        const int p = s & 1;
        act[p][tid] = ((tid >> 6) == 2) ? tanhf_fast(a) : sigf(a);
        __syncthreads();
        const float iv = act[p][lane], fv = act[p][64 + lane];
        const float gg = act[p][128 + lane], ov = act[p][192 + lane];
        c = fmaf(fv, c, iv * gg);
        h = ov * tanhf_fast(c);
        if (tid < 64) {
            const int t = dir ? (TT - 1 - s) : s;
            hob[(size_t)t * 128] = h;
        }
        g0 = g1; g1 = g2;
    }
}

// emissions = feats @ lin_w^T + lin_b ; 64 (b,t) rows x 41 classes per block
__global__ __launch_bounds__(256, 2) void emis_kernel(
    const float* __restrict__ feats, const float* __restrict__ lw,
    const float* __restrict__ lb, float* __restrict__ e)
{
    __shared__ float sf[64 * 132];
    __shared__ float swt[41 * 132];
    const int tid = threadIdx.x;
    const size_t bt0 = (size_t)blockIdx.x * 64;

    const float4* fs = (const float4*)(feats + bt0 * 128);
#pragma unroll
    for (int q = 0; q < 8; ++q) {
        const int idx = tid + q * 256;
        const int row = idx >> 5, col = idx & 31;
        *(float4*)&sf[row * 132 + col * 4] = fs[idx];
    }
    for (int idx = tid; idx < 41 * 32; idx += 256) {
        const int row = idx >> 5, col = idx & 31;
        *(float4*)&swt[row * 132 + col * 4] = ((const float4*)lw)[idx];
    }
    __syncthreads();

    const int btg = tid >> 4;
    const int cg = tid & 15;
    const int c0 = cg * 3;
    float acc[4][3];
#pragma unroll
    for (int i = 0; i < 4; ++i)
#pragma unroll
        for (int j = 0; j < 3; ++j) acc[i][j] = 0.f;

    for (int k = 0; k < 128; k += 4) {
        float4 fv[4], wv[3];
#pragma unroll
        for (int i = 0; i < 4; ++i) fv[i] = *(const float4*)&sf[(btg * 4 + i) * 132 + k];
#pragma unroll
        for (int j = 0; j < 3; ++j) {
            const int c = (c0 + j < CC) ? (c0 + j) : (CC - 1);
            wv[j] = *(const float4*)&swt[c * 132 + k];
        }
#pragma unroll
        for (int i = 0; i < 4; ++i)
#pragma unroll
            for (int j = 0; j < 3; ++j) {
                acc[i][j] = fmaf(fv[i].x, wv[j].x, acc[i][j]);
                acc[i][j] = fmaf(fv[i].y, wv[j].y, acc[i][j]);
                acc[i][j] = fmaf(fv[i].z, wv[j].z, acc[i][j]);
                acc[i][j] = fmaf(fv[i].w, wv[j].w, acc[i][j]);
            }
    }
    __syncthreads();
    float* so = sf;
#pragma unroll
    for (int i = 0; i < 4; ++i)
#pragma unroll
        for (int j = 0; j < 3; ++j) {
            const int c = c0 + j;
            if (c < CC) so[(btg * 4 + i) * CC + c] = acc[i][j] + lb[c];
        }
    __syncthreads();
    float* eo = e + bt0 * CC;
    for (int q = tid; q < 64 * CC; q += 256) eo[q] = so[q];
}

__global__ __launch_bounds__(64, 1) void viterbi_kernel(
    const float* __restrict__ e, const float* __restrict__ st,
    const float* __restrict__ en, const float* __restrict__ tr,
    int* __restrict__ out)
{
    const int b = blockIdx.x;
    const int lane = threadIdx.x;
    __shared__ unsigned char bp[TT][CC];
    __shared__ float sc[2][CC];
    const int c = (lane < CC) ? lane : (CC - 1);
    float trc[CC];
#pragma unroll
    for (int p = 0; p < CC; ++p) trc[p] = tr[p * CC + c];

    const float* eb = e + (size_t)b * TT * CC;
    const float NEG = -3.0e38f;
    if (lane < CC) sc[0][lane] = st[lane] + eb[lane];
    __syncthreads();

    for (int t = 1; t < TT; ++t) {
        const float* scp = sc[(t - 1) & 1];
        float best = NEG;
        int bi = 0;
#pragma unroll
        for (int p = 0; p < CC; ++p) {
            const float v = scp[p] + trc[p];
            if (v > best) { best = v; bi = p; }
        }
        if (lane < CC) {
            sc[t & 1][lane] = best + eb[(size_t)t * CC + lane];
            bp[t][lane] = (unsigned char)bi;
        }
        __syncthreads();
    }

    float fin = (lane < CC) ? sc[(TT - 1) & 1][lane] + en[lane] : NEG;
    int idx = lane;
#pragma unroll
    for (int off = 32; off; off >>= 1) {
        const float v2 = __shfl_down(fin, off, 64);
        const int i2 = __shfl_down(idx, off, 64);
        if (v2 > fin || (v2 == fin && i2 < idx)) { fin = v2; idx = i2; }
    }
    int tag = __shfl(idx, 0, 64);
    if (lane == 0) {
        int* ob = out + (size_t)b * TT;
        ob[TT - 1] = tag;
        for (int t = TT - 1; t >= 1; --t) {
            tag = bp[t][tag];
            ob[t - 1] = tag;
        }
    }
}

extern "C" void kernel_launch(void* const* d_in, const int* in_sizes, int n_in,
                              void* d_out, int out_size, void* d_ws, size_t ws_size,
                              hipStream_t stream) {
    const float* x       = (const float*)d_in[0];   // [B,T,39]
    const float* w_ih_l0 = (const float*)d_in[1];   // [2,256,39]  -> [512,39]
    const float* w_hh_l0 = (const float*)d_in[2];   // [2,256,64]
    const float* b_l0    = (const float*)d_in[3];   // [2,256]     -> [512]
    const float* w_ih_r  = (const float*)d_in[4];   // [2,2,256,128]
    const float* w_hh_r  = (const float*)d_in[5];   // [2,2,256,64]
    const float* b_r     = (const float*)d_in[6];   // [2,2,256]
    const float* lin_w   = (const float*)d_in[7];   // [41,128]
    const float* lin_b   = (const float*)d_in[8];   // [41]
    const float* crf_s   = (const float*)d_in[9];
    const float* crf_e   = (const float*)d_in[10];
    const float* crf_t   = (const float*)d_in[11];  // [41,41]
    int* out = (int*)d_out;

    float* h_buf  = (float*)d_ws;                        // [B,T,128] 128 MiB
    float* gx_buf = h_buf + (size_t)BB * TT * 128;       // chunked [nc,T,512]

    const size_t H_BYTES = (size_t)BB * TT * 128 * 4;
    const size_t ROW_GX  = (size_t)TT * 512 * 4;         // 2 MiB per batch row
    size_t avail = (ws_size > H_BYTES) ? (ws_size - H_BYTES) : ROW_GX;
    int chunk = (int)(avail / ROW_GX);
    if (chunk < 1) chunk = 1;
    if (chunk > BB) chunk = BB;

    for (int layer = 0; layer < 3; ++layer) {
        const float* W; const float* bias; const float* whh; int K;
        if (layer == 0) { W = w_ih_l0; bias = b_l0; whh = w_hh_l0; K = 39; }
        else {
            const int l = layer - 1;
            W = w_ih_r + (size_t)l * 512 * 128;
            bias = b_r + (size_t)l * 512;
            whh = w_hh_r + (size_t)l * 512 * 64;
            K = 128;
        }
        for (int c0 = 0; c0 < BB; c0 += chunk) {
            const int nc = (BB - c0 < chunk) ? (BB - c0) : chunk;
            const float* Ap = (layer == 0) ? (x + (size_t)c0 * TT * 39)
                                           : (h_buf + (size_t)c0 * TT * 128);
            dim3 ggrid(nc * 8, 4);
            if (layer == 0)
                gemm_bias_kernel<false><<<ggrid, 256, 0, stream>>>(
                    Ap, W, bias, gx_buf, nc * TT, 512, K);
            else
                gemm_bias_kernel<true><<<ggrid, 256, 0, stream>>>(
                    Ap, W, bias, gx_buf, nc * TT, 512, K);
            dim3 rgrid(nc, 2);
            recur_kernel<<<rgrid, 256, 0, stream>>>(gx_buf, whh, h_buf, c0);
        }
    }

    float* e_buf = gx_buf;  // [B,T,41] = 41 MiB, fits in gx region
    emis_kernel<<<BB * TT / 64, 256, 0, stream>>>(h_buf, lin_w, lin_b, e_buf);
    viterbi_kernel<<<BB, 64, 0, stream>>>(e_buf, crf_s, crf_e, crf_t, out);
}